// Round 6
// baseline (180.934 us; speedup 1.0000x reference)
//
#include <hip/hip_runtime.h>
#include <hip/hip_bf16.h>

// NA Spatial MSA, fused:  out = attn @ (xw @ (Wv@Wo)) + bo
// R6: cross-window software pipeline (R3 redo, bugs fixed).
// 1024 blocks x 4 consecutive windows, 80KB LDS double-buffer.
// Per iter: issue next-window loads (10 NAMED f32x4 regs - no arrays!) ->
// GEMM1 -> in-reg GEMM2 B-frags -> ds_write prefetch -> GEMM2 -> store ->
// lgkmcnt(0)+s_barrier (no vmcnt drain: stores + nothing else in flight).
// Goal: continuous mixed read+write HBM traffic (R5 showed phase-serialized
// engines at 39% BW).

typedef __bf16 bf16x8 __attribute__((ext_vector_type(8)));
typedef __bf16 bf16x4 __attribute__((ext_vector_type(4)));
typedef float  f32x16 __attribute__((ext_vector_type(16)));
typedef float  f32x4  __attribute__((ext_vector_type(4)));
typedef unsigned int uint;
typedef uint   uint4v __attribute__((ext_vector_type(4)));

#define MFMA32(a, b, c) __builtin_amdgcn_mfma_f32_32x32x16_bf16(a, b, c, 0, 0, 0)

// ---------------- Stage 0: WT = (Wv @ Wo)^T in bf16 ----------------
__global__ void wfuse_kernel(const float* __restrict__ Wv,
                             const float* __restrict__ Wo,
                             __bf16* __restrict__ WT) {
  const int n = blockIdx.x;    // output channel (col of W)
  const int k = threadIdx.x;   // input channel  (row of W)
  const float* wvrow = Wv + k * 256;
  float acc = 0.f;
#pragma unroll 4
  for (int j = 0; j < 256; j += 4) {
    f32x4 wv = *(const f32x4*)(wvrow + j);
    acc += wv.x * Wo[(j + 0) * 256 + n];
    acc += wv.y * Wo[(j + 1) * 256 + n];
    acc += wv.z * Wo[(j + 2) * 256 + n];
    acc += wv.w * Wo[(j + 3) * 256 + n];
  }
  WT[n * 256 + k] = (__bf16)acc;
}

// pack two f32 -> one u32 of two bf16 (lo = first)
static __device__ __forceinline__ uint pkbf(float lo, float hi) {
  return (uint)__builtin_bit_cast(unsigned short, (__bf16)lo) |
         ((uint)__builtin_bit_cast(unsigned short, (__bf16)hi) << 16);
}

// Build 2 GEMM2 B-frags (k-slices of 16) from one GEMM1 acc (32 toks).
// acc reg 4g+r holds z[tok = T + 8g + 4*lh + r][ch = lane&31 (+32*wv base)].
// B-frag word j must hold toks (T + ks*16 + 8*lh + 2j, +2j+1).  (verified R3/R5)
static __device__ __forceinline__ void build_bfrags(const f32x16 acc, int lh,
                                                    bf16x8* bf) {
  uint wd0 = pkbf(acc[0],  acc[1]);
  uint wd1 = pkbf(acc[2],  acc[3]);
  uint wd2 = pkbf(acc[4],  acc[5]);
  uint wd3 = pkbf(acc[6],  acc[7]);
  uint wd4 = pkbf(acc[8],  acc[9]);
  uint wd5 = pkbf(acc[10], acc[11]);
  uint wd6 = pkbf(acc[12], acc[13]);
  uint wd7 = pkbf(acc[14], acc[15]);
  {
    uint o0 = (uint)__shfl_xor((int)wd2, 32);
    uint o1 = (uint)__shfl_xor((int)wd3, 32);
    uint o2 = (uint)__shfl_xor((int)wd0, 32);
    uint o3 = (uint)__shfl_xor((int)wd1, 32);
    uint4v uv = { lh ? o0 : wd0, lh ? o1 : wd1,
                  lh ? wd2 : o2, lh ? wd3 : o3 };
    bf[0] = __builtin_bit_cast(bf16x8, uv);
  }
  {
    uint o0 = (uint)__shfl_xor((int)wd6, 32);
    uint o1 = (uint)__shfl_xor((int)wd7, 32);
    uint o2 = (uint)__shfl_xor((int)wd4, 32);
    uint o3 = (uint)__shfl_xor((int)wd5, 32);
    uint4v uv = { lh ? o0 : wd4, lh ? o1 : wd5,
                  lh ? wd6 : o2, lh ? wd7 : o3 };
    bf[1] = __builtin_bit_cast(bf16x8, uv);
  }
}

// window base offset in x/out (float index)
static __device__ __forceinline__ long wbase(int w) {
  int wi = w & 31;
  int hi = (w >> 5) & 31;
  int b  = w >> 10;
  return (((long)(b * 256 + hi * 8)) * 256 + wi * 8) * 256;
}

// ---------------- Main kernel ----------------
// LDS: 2 buffers x (32KB xw bf16 swizzled + 8KB attn bf16 swizzled) = 80KB.
__global__ __launch_bounds__(512)
__attribute__((amdgpu_waves_per_eu(4, 4)))
void na_msa_kernel(const float* __restrict__ x,
                   const float* __restrict__ attn,
                   const __bf16* __restrict__ WT,
                   const float* __restrict__ bo,
                   float* __restrict__ out) {
  __shared__ char lds[81920];

  const int t    = threadIdx.x;
  const int lane = t & 63;
  const int wvi  = t >> 6;              // wave 0..7, owns ch [32wvi, 32wvi+32)
  const int ln31 = lane & 31;
  const int lh   = lane >> 5;           // 0 or 1 (K-half of the wave)

  // staging geometry (per-thread constants)
  const int tq   = t >> 6;              // x: token-sub within h-row chunk
  const int xch0 = (t & 63) * 4;        // x: first channel of this thread's 4
  const int arow0 = t >> 4;             // attn: row for chunk 0 (chunk1: +32)
  const int ak0  = (t & 15) * 4;        // attn: first k of this thread's 4

  const __bf16* wtp = WT + (wvi * 32 + ln31) * 256 + 8 * lh;
  const float bv = bo[wvi * 32 + ln31];

  const int w0 = blockIdx.x * 4;

// x chunk j (h-row j): load float4 at xp + j*65536 + t*4; tok = j*8+tq
#define XBYT(J)  ((((J) * 8 + tq) * 512) + ((xch0 * 2) ^ (((((J) * 8 + tq)) & 31) << 4)))
#define ABYT(I)  (((I) * 32 + arow0) * 128 + ((ak0 * 2) ^ ((((I) * 32 + arow0) & 7) << 4)))
#define CVT4(V)  bf16x4{ (__bf16)(V).x, (__bf16)(V).y, (__bf16)(V).z, (__bf16)(V).w }

  // ---- prologue: stage window w0 into buf0 ----
  {
    const float* xp = x + wbase(w0);
    const float* ap = attn + (long)w0 * 4096;
    f32x4 v0 = *(const f32x4*)(xp + 0 * 65536 + t * 4);
    f32x4 v1 = *(const f32x4*)(xp + 1 * 65536 + t * 4);
    f32x4 v2 = *(const f32x4*)(xp + 2 * 65536 + t * 4);
    f32x4 v3 = *(const f32x4*)(xp + 3 * 65536 + t * 4);
    f32x4 v4 = *(const f32x4*)(xp + 4 * 65536 + t * 4);
    f32x4 v5 = *(const f32x4*)(xp + 5 * 65536 + t * 4);
    f32x4 v6 = *(const f32x4*)(xp + 6 * 65536 + t * 4);
    f32x4 v7 = *(const f32x4*)(xp + 7 * 65536 + t * 4);
    f32x4 a0 = *(const f32x4*)(ap + t * 4);
    f32x4 a1 = *(const f32x4*)(ap + (512 + t) * 4);
    *(bf16x4*)(lds + XBYT(0)) = CVT4(v0);
    *(bf16x4*)(lds + XBYT(1)) = CVT4(v1);
    *(bf16x4*)(lds + XBYT(2)) = CVT4(v2);
    *(bf16x4*)(lds + XBYT(3)) = CVT4(v3);
    *(bf16x4*)(lds + XBYT(4)) = CVT4(v4);
    *(bf16x4*)(lds + XBYT(5)) = CVT4(v5);
    *(bf16x4*)(lds + XBYT(6)) = CVT4(v6);
    *(bf16x4*)(lds + XBYT(7)) = CVT4(v7);
    *(bf16x4*)(lds + 32768 + ABYT(0)) = CVT4(a0);
    *(bf16x4*)(lds + 32768 + ABYT(1)) = CVT4(a1);
  }
  asm volatile("s_waitcnt lgkmcnt(0)" ::: "memory");
  __builtin_amdgcn_s_barrier();
  __builtin_amdgcn_sched_barrier(0);

#pragma unroll 1
  for (int i = 0; i < 4; ++i) {
    const int w = w0 + i;
    char* lds_xw = lds + (i & 1) * 40960;
    char* lds_at = lds_xw + 32768;

    // ---- issue next window's global loads (named regs only; T14) ----
    f32x4 px0, px1, px2, px3, px4, px5, px6, px7, pa0, pa1;
    if (i < 3) {
      const float* xp = x + wbase(w + 1);
      const float* ap = attn + (long)(w + 1) * 4096;
      px0 = *(const f32x4*)(xp + 0 * 65536 + t * 4);
      px1 = *(const f32x4*)(xp + 1 * 65536 + t * 4);
      px2 = *(const f32x4*)(xp + 2 * 65536 + t * 4);
      px3 = *(const f32x4*)(xp + 3 * 65536 + t * 4);
      px4 = *(const f32x4*)(xp + 4 * 65536 + t * 4);
      px5 = *(const f32x4*)(xp + 5 * 65536 + t * 4);
      px6 = *(const f32x4*)(xp + 6 * 65536 + t * 4);
      px7 = *(const f32x4*)(xp + 7 * 65536 + t * 4);
      pa0 = *(const f32x4*)(ap + t * 4);
      pa1 = *(const f32x4*)(ap + (512 + t) * 4);
    }
    __builtin_amdgcn_sched_barrier(0);   // pin: loads issued before GEMM1

    // ---- GEMM1: z[tok][ch] = xw @ W, K=256 ----
    f32x16 acc0 = {}, acc1 = {};
#pragma unroll 2
    for (int ks = 0; ks < 16; ++ks) {
      int kk = ks * 16 + 8 * lh;
      int byt0 = ln31 * 512 + ((kk * 2) ^ (ln31 << 4));
      bf16x8 a0 = *(const bf16x8*)(lds_xw + byt0);            // toks 0..31
      bf16x8 a1 = *(const bf16x8*)(lds_xw + byt0 + 16384);    // toks 32..63
      bf16x8 b0 = *(const bf16x8*)(wtp + ks * 16);            // L2-resident
      acc0 = MFMA32(a0, b0, acc0);
      acc1 = MFMA32(a1, b0, acc1);
    }
    __builtin_amdgcn_sched_barrier(0);   // keep GEMM1 clear of vmcnt waits

    // ---- GEMM2 B-frags in-register ----
    bf16x8 bfr[4];
    build_bfrags(acc0, lh, &bfr[0]);   // ks 0,1 (toks 0..31)
    build_bfrags(acc1, lh, &bfr[2]);   // ks 2,3 (toks 32..63)

    // ---- write prefetched window to the other buffer (named stmts) ----
    if (i < 3) {
      char* bxw = lds + ((i + 1) & 1) * 40960;
      char* bat = bxw + 32768;
      *(bf16x4*)(bxw + XBYT(0)) = CVT4(px0);
      *(bf16x4*)(bxw + XBYT(1)) = CVT4(px1);
      *(bf16x4*)(bxw + XBYT(2)) = CVT4(px2);
      *(bf16x4*)(bxw + XBYT(3)) = CVT4(px3);
      *(bf16x4*)(bxw + XBYT(4)) = CVT4(px4);
      *(bf16x4*)(bxw + XBYT(5)) = CVT4(px5);
      *(bf16x4*)(bxw + XBYT(6)) = CVT4(px6);
      *(bf16x4*)(bxw + XBYT(7)) = CVT4(px7);
      *(bf16x4*)(bat + ABYT(0)) = CVT4(pa0);
      *(bf16x4*)(bat + ABYT(1)) = CVT4(pa1);
    }

    // ---- GEMM2: out[tok][ch] = attn @ z, K=64 ----
    f32x16 o0 = {}, o1 = {};
#pragma unroll
    for (int ks = 0; ks < 4; ++ks) {
      int kk = ks * 16 + 8 * lh;
      int ab0 = ln31 * 128 + ((kk * 2) ^ ((ln31 & 7) << 4));
      bf16x8 a0 = *(const bf16x8*)(lds_at + ab0);             // out-toks 0..31
      bf16x8 a1 = *(const bf16x8*)(lds_at + ab0 + 4096);      // out-toks 32..63
      o0 = MFMA32(a0, bfr[ks], o0);
      o1 = MFMA32(a1, bfr[ks], o1);
    }

    // ---- epilogue: + bo, scatter-store window w ----
    {
      float* op = out + wbase(w);
      const int ch = wvi * 32 + ln31;
#pragma unroll
      for (int r = 0; r < 16; ++r) {
        int tok = (r & 3) + 8 * (r >> 2) + 4 * lh;            // o0: toks 0..31
        op[(tok >> 3) * 65536 + (tok & 7) * 256 + ch] = o0[r] + bv;
      }
#pragma unroll
      for (int r = 0; r < 16; ++r) {
        int tok = 32 + (r & 3) + 8 * (r >> 2) + 4 * lh;       // o1: toks 32..63
        op[(tok >> 3) * 65536 + (tok & 7) * 256 + ch] = o1[r] + bv;
      }
    }

    // ---- barrier WITHOUT vmcnt drain: stores stay in flight ----
    asm volatile("s_waitcnt lgkmcnt(0)" ::: "memory");
    __builtin_amdgcn_s_barrier();
    __builtin_amdgcn_sched_barrier(0);
  }
}

extern "C" void kernel_launch(void* const* d_in, const int* in_sizes, int n_in,
                              void* d_out, int out_size, void* d_ws, size_t ws_size,
                              hipStream_t stream) {
  const float* x    = (const float*)d_in[0];
  const float* attn = (const float*)d_in[1];
  const float* Wv   = (const float*)d_in[2];
  const float* Wo   = (const float*)d_in[3];
  const float* bo   = (const float*)d_in[4];
  float* out = (float*)d_out;
  __bf16* WT = (__bf16*)d_ws;   // 256*256*2 = 128 KB scratch

  wfuse_kernel<<<256, 256, 0, stream>>>(Wv, Wo, WT);
  na_msa_kernel<<<1024, 512, 0, stream>>>(x, attn, WT, bo, out);
}

// Round 7
// 173.244 us; speedup vs baseline: 1.0444x; 1.0444x over previous
//
#include <hip/hip_runtime.h>
#include <hip/hip_bf16.h>

// NA Spatial MSA, fused:  out = attn @ (xw @ (Wv@Wo)) + bo
// R7: persistent pipeline with global_load_lds staging (zero staging VGPRs).
// 256 blocks (1/CU) x 16 windows. LDS 144KB: 2x 64KB x-strip (RAW F32,
// source-pre-swizzled, cvt folded into frag reads) + 2x 8KB attn bf16 (R5's
// proven path, cvt+ds_write placed after stores so its wait is hidden).
// One vmcnt(0) per window: the 8 DMAs are a full compute-phase old -> free.

typedef __bf16 bf16x8 __attribute__((ext_vector_type(8)));
typedef __bf16 bf16x4 __attribute__((ext_vector_type(4)));
typedef float  f32x16 __attribute__((ext_vector_type(16)));
typedef float  f32x4  __attribute__((ext_vector_type(4)));
typedef unsigned int uint;
typedef uint   uint4v __attribute__((ext_vector_type(4)));

#define MFMA32(a, b, c) __builtin_amdgcn_mfma_f32_32x32x16_bf16(a, b, c, 0, 0, 0)

// ---------------- Stage 0: WT = (Wv @ Wo)^T in bf16 ----------------
__global__ void wfuse_kernel(const float* __restrict__ Wv,
                             const float* __restrict__ Wo,
                             __bf16* __restrict__ WT) {
  const int n = blockIdx.x;
  const int k = threadIdx.x;
  const float* wvrow = Wv + k * 256;
  float acc = 0.f;
#pragma unroll 4
  for (int j = 0; j < 256; j += 4) {
    f32x4 wv = *(const f32x4*)(wvrow + j);
    acc += wv.x * Wo[(j + 0) * 256 + n];
    acc += wv.y * Wo[(j + 1) * 256 + n];
    acc += wv.z * Wo[(j + 2) * 256 + n];
    acc += wv.w * Wo[(j + 3) * 256 + n];
  }
  WT[n * 256 + k] = (__bf16)acc;
}

static __device__ __forceinline__ uint pkbf(float lo, float hi) {
  return (uint)__builtin_bit_cast(unsigned short, (__bf16)lo) |
         ((uint)__builtin_bit_cast(unsigned short, (__bf16)hi) << 16);
}

// GEMM2 B-frags from GEMM1 acc via pack + shfl_xor(32). (verified R3/R5)
static __device__ __forceinline__ void build_bfrags(const f32x16 acc, int lh,
                                                    bf16x8* bf) {
  uint wd0 = pkbf(acc[0],  acc[1]);
  uint wd1 = pkbf(acc[2],  acc[3]);
  uint wd2 = pkbf(acc[4],  acc[5]);
  uint wd3 = pkbf(acc[6],  acc[7]);
  uint wd4 = pkbf(acc[8],  acc[9]);
  uint wd5 = pkbf(acc[10], acc[11]);
  uint wd6 = pkbf(acc[12], acc[13]);
  uint wd7 = pkbf(acc[14], acc[15]);
  {
    uint o0 = (uint)__shfl_xor((int)wd2, 32);
    uint o1 = (uint)__shfl_xor((int)wd3, 32);
    uint o2 = (uint)__shfl_xor((int)wd0, 32);
    uint o3 = (uint)__shfl_xor((int)wd1, 32);
    uint4v uv = { lh ? o0 : wd0, lh ? o1 : wd1,
                  lh ? wd2 : o2, lh ? wd3 : o3 };
    bf[0] = __builtin_bit_cast(bf16x8, uv);
  }
  {
    uint o0 = (uint)__shfl_xor((int)wd6, 32);
    uint o1 = (uint)__shfl_xor((int)wd7, 32);
    uint o2 = (uint)__shfl_xor((int)wd4, 32);
    uint o3 = (uint)__shfl_xor((int)wd5, 32);
    uint4v uv = { lh ? o0 : wd4, lh ? o1 : wd5,
                  lh ? wd6 : o2, lh ? wd7 : o3 };
    bf[1] = __builtin_bit_cast(bf16x8, uv);
  }
}

static __device__ __forceinline__ long wbase(int w) {
  int wi = w & 31;
  int hi = (w >> 5) & 31;
  int b  = w >> 10;
  return (((long)(b * 256 + hi * 8)) * 256 + wi * 8) * 256;
}

// async 16B/lane global->LDS DMA (LDS dest = wave-uniform base + lane*16)
static __device__ __forceinline__ void dma16(const float* gp, char* lp) {
  __builtin_amdgcn_global_load_lds(
      (const __attribute__((address_space(1))) uint*)gp,
      (__attribute__((address_space(3))) uint*)lp, 16, 0, 0);
}

// read bf16x8 A-frag from f32 x-strip (swizzle: granule p = g ^ (tok&31))
static __device__ __forceinline__ bf16x8 ldax(const char* xs, int tok, int g) {
  const int sw = tok & 31;
  f32x4 u = *(const f32x4*)(xs + tok * 1024 + ((g ^ sw) << 4));
  f32x4 v = *(const f32x4*)(xs + tok * 1024 + (((g + 1) ^ sw) << 4));
  bf16x8 r;
  r[0] = (__bf16)u.x; r[1] = (__bf16)u.y; r[2] = (__bf16)u.z; r[3] = (__bf16)u.w;
  r[4] = (__bf16)v.x; r[5] = (__bf16)v.y; r[6] = (__bf16)v.z; r[7] = (__bf16)v.w;
  return r;
}

// ---------------- Main kernel ----------------
// LDS 144KB: x-f32 strips at 0 / 65536; attn-bf16 strips at 131072 / 139264.
__global__ __launch_bounds__(512)
void na_msa_kernel(const float* __restrict__ x,
                   const float* __restrict__ attn,
                   const __bf16* __restrict__ WT,
                   const float* __restrict__ bo,
                   float* __restrict__ out) {
  __shared__ char lds[147456];

  const int t    = threadIdx.x;
  const int lane = t & 63;
  const int wvi  = t >> 6;              // wave 0..7, owns ch [32wvi, 32wvi+32)
  const int ln31 = lane & 31;
  const int lh   = lane >> 5;

  const __bf16* wtp = WT + (wvi * 32 + ln31) * 256 + 8 * lh;
  const float bv = bo[wvi * 32 + ln31];

  // attn VGPR-staging geometry (R5): thread t handles f32x4 idx {t, 512+t}
  const int arow0 = t >> 4;             // row for chunk 0 (chunk 1: +32)
  const int ak0   = (t & 15) * 4;

  const int w0 = blockIdx.x * 16;

  // ---- x DMA staging: 8 instrs; wave wvi loads tok = j*8+wvi, lane l holds
  // ch-granule (l ^ (tok&31)); LDS dest linear -> swizzled tile emerges. ----
#define STAGE_X(W, BUFOFF) do {                                            \
    const float* xp_ = x + wbase(W);                                       \
    _Pragma("unroll")                                                      \
    for (int j = 0; j < 8; ++j) {                                          \
      int tok_ = j * 8 + wvi;                                              \
      int ch0_ = (lane ^ (tok_ & 31)) * 4;                                 \
      const float* gp_ = xp_ + (tok_ >> 3) * 65536 + (tok_ & 7) * 256 + ch0_; \
      int off_ = __builtin_amdgcn_readfirstlane((BUFOFF) + j * 8192 + wvi * 1024); \
      dma16(gp_, lds + off_);                                              \
    } } while (0)

  // ---- prologue: stage window w0 into buffer 0 ----
  STAGE_X(w0, 0);
  {
    const float* ap = attn + (long)w0 * 4096;
    f32x4 a0 = *(const f32x4*)(ap + t * 4);
    f32x4 a1 = *(const f32x4*)(ap + (512 + t) * 4);
    char* bat = lds + 131072;
    *(bf16x4*)(bat + arow0 * 128 + ((ak0 * 2) ^ ((arow0 & 7) << 4))) =
        bf16x4{ (__bf16)a0.x, (__bf16)a0.y, (__bf16)a0.z, (__bf16)a0.w };
    int row1 = 32 + arow0;
    *(bf16x4*)(bat + row1 * 128 + ((ak0 * 2) ^ ((row1 & 7) << 4))) =
        bf16x4{ (__bf16)a1.x, (__bf16)a1.y, (__bf16)a1.z, (__bf16)a1.w };
  }
  asm volatile("s_waitcnt vmcnt(0) lgkmcnt(0)" ::: "memory");
  __builtin_amdgcn_s_barrier();
  __builtin_amdgcn_sched_barrier(0);

#pragma unroll 1
  for (int i = 0; i < 16; ++i) {
    const int w = w0 + i;
    const char* xs = lds + (i & 1) * 65536;
    const char* as = lds + 131072 + (i & 1) * 8192;

    // ---- 1+2: issue next window's attn loads (8 VGPRs) + x DMAs ----
    f32x4 ra0, ra1;
    if (i < 15) {
      const float* ap = attn + (long)(w + 1) * 4096;
      ra0 = *(const f32x4*)(ap + t * 4);
      ra1 = *(const f32x4*)(ap + (512 + t) * 4);
      STAGE_X(w + 1, ((i + 1) & 1) * 65536);
    }
    __builtin_amdgcn_sched_barrier(0);   // pin: all issues before GEMM1

    // ---- GEMM1: z[tok][ch] = xw @ W, K=256 (A from f32 LDS + cvt) ----
    f32x16 acc0 = {}, acc1 = {};
#pragma unroll 4
    for (int ks = 0; ks < 16; ++ks) {
      int g = 4 * ks + 2 * lh;
      bf16x8 a0 = ldax(xs, ln31, g);            // toks 0..31
      bf16x8 a1 = ldax(xs, 32 + ln31, g);       // toks 32..63
      bf16x8 b0 = *(const bf16x8*)(wtp + ks * 16);
      acc0 = MFMA32(a0, b0, acc0);
      acc1 = MFMA32(a1, b0, acc1);
    }

    // ---- GEMM2 B-frags in-register ----
    bf16x8 bfr[4];
    build_bfrags(acc0, lh, &bfr[0]);
    build_bfrags(acc1, lh, &bfr[2]);

    // ---- GEMM2: out[tok][ch] = attn @ z, K=64 (attn bf16 LDS, R5 path) ----
    f32x16 o0 = {}, o1 = {};
#pragma unroll
    for (int ks = 0; ks < 4; ++ks) {
      int kk = ks * 16 + 8 * lh;
      int ab0 = ln31 * 128 + ((kk * 2) ^ ((ln31 & 7) << 4));
      bf16x8 a0 = *(const bf16x8*)(as + ab0);
      bf16x8 a1 = *(const bf16x8*)(as + ab0 + 4096);
      o0 = MFMA32(a0, bfr[ks], o0);
      o1 = MFMA32(a1, bfr[ks], o1);
    }

    // ---- epilogue: + bo, scatter-store window w ----
    {
      float* op = out + wbase(w);
      const int ch = wvi * 32 + ln31;
#pragma unroll
      for (int r = 0; r < 16; ++r) {
        int tok = (r & 3) + 8 * (r >> 2) + 4 * lh;
        op[(tok >> 3) * 65536 + (tok & 7) * 256 + ch] = o0[r] + bv;
      }
#pragma unroll
      for (int r = 0; r < 16; ++r) {
        int tok = 32 + (r & 3) + 8 * (r >> 2) + 4 * lh;
        op[(tok >> 3) * 65536 + (tok & 7) * 256 + ch] = o1[r] + bv;
      }
    }

    // ---- 7: attn cvt + ds_write for w+1 (auto-vmcnt here is hidden) ----
    if (i < 15) {
      char* bat = lds + 131072 + ((i + 1) & 1) * 8192;
      *(bf16x4*)(bat + arow0 * 128 + ((ak0 * 2) ^ ((arow0 & 7) << 4))) =
          bf16x4{ (__bf16)ra0.x, (__bf16)ra0.y, (__bf16)ra0.z, (__bf16)ra0.w };
      int row1 = 32 + arow0;
      *(bf16x4*)(bat + row1 * 128 + ((ak0 * 2) ^ ((row1 & 7) << 4))) =
          bf16x4{ (__bf16)ra1.x, (__bf16)ra1.y, (__bf16)ra1.z, (__bf16)ra1.w };
    }

    // ---- 8: drain (DMAs long done; only ~32 stores wait) + barrier ----
    asm volatile("s_waitcnt vmcnt(0) lgkmcnt(0)" ::: "memory");
    __builtin_amdgcn_s_barrier();
    __builtin_amdgcn_sched_barrier(0);
  }
#undef STAGE_X
}

extern "C" void kernel_launch(void* const* d_in, const int* in_sizes, int n_in,
                              void* d_out, int out_size, void* d_ws, size_t ws_size,
                              hipStream_t stream) {
  const float* x    = (const float*)d_in[0];
  const float* attn = (const float*)d_in[1];
  const float* Wv   = (const float*)d_in[2];
  const float* Wo   = (const float*)d_in[3];
  const float* bo   = (const float*)d_in[4];
  float* out = (float*)d_out;
  __bf16* WT = (__bf16*)d_ws;   // 256*256*2 = 128 KB scratch

  wfuse_kernel<<<256, 256, 0, stream>>>(Wv, Wo, WT);
  na_msa_kernel<<<256, 512, 0, stream>>>(x, attn, WT, bo, out);
}